// Round 1
// 484.883 us; speedup vs baseline: 1.0978x; 1.0978x over previous
//
#include <hip/hip_runtime.h>
#include <stdint.h>

#define C 128

typedef __attribute__((ext_vector_type(8))) short bfrag;   // 8 x bf16 (4 VGPRs)
typedef __attribute__((ext_vector_type(4))) float ffrag;   // 4 x f32 accum

__device__ __forceinline__ unsigned short f2bf(float f){
  union { float f; unsigned int i; } v; v.f = f;
  unsigned int x = v.i;
  unsigned int r = x + 0x7fffu + ((x >> 16) & 1u);   // round-to-nearest-even
  return (unsigned short)(r >> 16);
}
__device__ __forceinline__ float bf2f(unsigned short u){
  union { unsigned int i; float f; } v; v.i = ((unsigned int)u) << 16; return v.f;
}

// ---------------- misc small kernels ----------------

__global__ void k_zero(float* a, int* b, int n){
  int i = blockIdx.x * 256 + threadIdx.x;
  if (i < n){ if (a) a[i] = 0.f; if (b) b[i] = 0; }
}

__global__ void k_cast(const float* __restrict__ src, unsigned short* __restrict__ dst, int n){
  int i = blockIdx.x * 256 + threadIdx.x;
  if (i < n) dst[i] = f2bf(src[i]);
}

// merged deg+cnt: one u64 atomic per edge.
//   high 32 bits: edge count; low 32 bits: weight in 24-bit fixed point.
//   returned old value gives this edge's rank within its row for free.
__global__ void k_degcnt(const int* __restrict__ row, const float* __restrict__ w,
                         unsigned long long* deg64, int* __restrict__ rank, int E){
  int e = blockIdx.x * 256 + threadIdx.x;
  if (e < E){
    int r = row[e];
    unsigned int wf = (unsigned int)(w[e] * 16777216.0f + 0.5f);   // w * 2^24
    unsigned long long old =
        atomicAdd(&deg64[r], 0x100000000ULL | (unsigned long long)wf);
    rank[e] = (int)(old >> 32);
  }
}

// decode deg64 -> dinv (float) and cnt (int)
__global__ void k_decode(const unsigned long long* __restrict__ deg64,
                         float* __restrict__ dinv, int* __restrict__ cnt, int N){
  int i = blockIdx.x * 256 + threadIdx.x;
  if (i < N){
    unsigned long long v = deg64[i];
    unsigned int lo = (unsigned int)v;
    cnt[i] = (int)(v >> 32);
    float d = (float)lo * (1.0f / 16777216.0f);
    dinv[i] = lo > 0u ? 1.0f / sqrtf(d) : 0.f;
  }
}

// ---- 3-stage coalesced scan of cnt -> row_ptr ----
__global__ void k_scan1(const int* __restrict__ cnt, int* bsum, int N){
  __shared__ int s[256];
  int b = blockIdx.x, t = threadIdx.x;
  int i = b * 256 + t;
  s[t] = (i < N) ? cnt[i] : 0;
  __syncthreads();
  for (int o = 128; o; o >>= 1){ if (t < o) s[t] += s[t + o]; __syncthreads(); }
  if (t == 0) bsum[b] = s[0];
}
__global__ void k_scan2(const int* __restrict__ bsum, int* bbase, int nb){
  __shared__ int s[256];
  int t = threadIdx.x;
  s[t] = (t < nb) ? bsum[t] : 0;
  __syncthreads();
  for (int o = 1; o < 256; o <<= 1){
    int v = (t >= o) ? s[t - o] : 0;
    __syncthreads(); s[t] += v; __syncthreads();
  }
  if (t < nb) bbase[t] = (t > 0) ? s[t - 1] : 0;   // exclusive
}
__global__ void k_scan3(const int* __restrict__ cnt, const int* __restrict__ bbase,
                        int* row_ptr, int N){
  __shared__ int s[256];
  int b = blockIdx.x, t = threadIdx.x;
  int i = b * 256 + t;
  int v = (i < N) ? cnt[i] : 0;
  s[t] = v;
  __syncthreads();
  for (int o = 1; o < 256; o <<= 1){
    int u = (t >= o) ? s[t - o] : 0;
    __syncthreads(); s[t] += u; __syncthreads();
  }
  int excl = bbase[b] + s[t] - v;
  if (i < N) row_ptr[i] = excl;
  if (i == N - 1) row_ptr[N] = excl + v;
}

// atomic-free CSR fill: p = row_ptr[r] + rank[e]; packed (col, coef) 8B store
__global__ void k_fill(const int* __restrict__ row, const int* __restrict__ col,
                       const float* __restrict__ w, const int* __restrict__ rank,
                       const int* __restrict__ row_ptr, const float* __restrict__ dinv,
                       int2* __restrict__ edge_s, int E){
  int e = blockIdx.x * 256 + threadIdx.x;
  if (e < E){
    int r = row[e], c = col[e];
    int p = row_ptr[r] + rank[e];
    float cf = dinv[r] * dinv[c] * w[e];
    int2 ed; ed.x = c; ed.y = __float_as_int(cf);
    edge_s[p] = ed;
  }
}

// cur16 = bf16(x); accf = x (fp32)
__global__ void k_init(const float* __restrict__ x, unsigned short* cur16, float* accf, int total){
  int i = blockIdx.x * 256 + threadIdx.x;
  if (i < total){ float v = x[i]; cur16[i] = f2bf(v); accf[i] = v; }
}

// src [N][C] bf16 -> dst [C][N] bf16 (LDS-tiled 64x64)
__global__ void k_transpose(const unsigned short* __restrict__ src, unsigned short* __restrict__ dst, int N){
  __shared__ unsigned short tile[64][66];
  int n0 = blockIdx.x * 64, c0 = blockIdx.y * 64;
  int tx = threadIdx.x & 63;
  int ty = threadIdx.x >> 6;
  for (int r = ty; r < 64; r += 4) tile[r][tx] = src[(size_t)(n0 + r) * C + c0 + tx];
  __syncthreads();
  for (int r = ty; r < 64; r += 4) dst[(size_t)(c0 + r) * N + n0 + tx] = tile[tx][r];
}

// ---------------- projection [MFMA]; transposed=1 also accumulates ksum ----------------
__global__ __launch_bounds__(256) void k_proj(const unsigned short* __restrict__ x,
      const unsigned short* __restrict__ W, const float* __restrict__ Wb,
      unsigned short* __restrict__ out, float* __restrict__ ksum,
      int N, int PG, int transposed){
  int wv = threadIdx.x >> 6, l = threadIdx.x & 63;
  int m0 = (blockIdx.x * 4 + wv) * 16;
  if (m0 >= N) return;
  int quad = l >> 4, lcol = l & 15;
  ffrag acc[8] = {};
  const unsigned short* Abase = x + (size_t)(m0 + lcol) * C + quad * 8;
#pragma unroll
  for (int s = 0; s < 4; s++){
    bfrag a = *(const bfrag*)(Abase + s * 32);
#pragma unroll
    for (int nt = 0; nt < 8; nt++){
      bfrag bb = *(const bfrag*)(W + (size_t)(nt * 16 + lcol) * C + s * 32 + quad * 8);
      acc[nt] = __builtin_amdgcn_mfma_f32_16x16x32_bf16(a, bb, acc[nt], 0, 0, 0);
    }
  }
  float q[8][4];
  float ss[4] = {0.f, 0.f, 0.f, 0.f};
#pragma unroll
  for (int nt = 0; nt < 8; nt++){
    float bias = Wb[nt * 16 + lcol];
#pragma unroll
    for (int r = 0; r < 4; r++){ float v = acc[nt][r] + bias; q[nt][r] = v; ss[r] += v * v; }
  }
#pragma unroll
  for (int off = 1; off < 16; off <<= 1){
#pragma unroll
    for (int r = 0; r < 4; r++) ss[r] += __shfl_xor(ss[r], off, 64);
  }
  float inv[4];
#pragma unroll
  for (int r = 0; r < 4; r++) inv[r] = 1.0f / sqrtf(fmaxf(ss[r], 1e-30f));
  if (!transposed){
#pragma unroll
    for (int nt = 0; nt < 8; nt++)
#pragma unroll
      for (int r = 0; r < 4; r++)
        out[(size_t)(m0 + quad * 4 + r) * C + nt * 16 + lcol] = f2bf(q[nt][r] * inv[r]);
  } else {
    int b = m0 / PG;
#pragma unroll
    for (int nt = 0; nt < 8; nt++){
      ushort4 pk;
      float v0 = q[nt][0] * inv[0], v1 = q[nt][1] * inv[1];
      float v2 = q[nt][2] * inv[2], v3 = q[nt][3] * inv[3];
      pk.x = f2bf(v0); pk.y = f2bf(v1); pk.z = f2bf(v2); pk.w = f2bf(v3);
      *(ushort4*)(out + (size_t)(nt * 16 + lcol) * N + m0 + quad * 4) = pk;
      float s = v0 + v1 + v2 + v3;
      s += __shfl_xor(s, 16, 64);
      s += __shfl_xor(s, 32, 64);
      if (quad == 0) atomicAdd(&ksum[b * C + nt * 16 + lcol], s);
    }
  }
}

__global__ void k_denom(const unsigned short* __restrict__ qs, const float* __restrict__ ksum,
                        const int* __restrict__ n_nodes, float* denom, int N, int PG){
  int wv = threadIdx.x >> 6, l = threadIdx.x & 63;
  int m = blockIdx.x * 4 + wv;
  if (m >= N) return;
  int b = m / PG;
  float s = bf2f(qs[(size_t)m * C + l]) * ksum[b * C + l]
          + bf2f(qs[(size_t)m * C + 64 + l]) * ksum[b * C + 64 + l];
#pragma unroll
  for (int off = 32; off; off >>= 1) s += __shfl_xor(s, off, 64);
  if (l == 0) denom[m] = s + (float)n_nodes[b];
}

// vsum of initial cur (only used once in prep)
__global__ void k_vsum(const unsigned short* __restrict__ cur16, float* vsum, int PG){
  int b = blockIdx.x, ch = blockIdx.y, c = threadIdx.x;
  int chunk = PG / 8;
  const unsigned short* p = cur16 + ((size_t)b * PG + ch * chunk) * C + c;
  float s = 0.f;
  for (int n = 0; n < chunk; n++) s += bf2f(p[(size_t)n * C]);
  atomicAdd(&vsum[b * C + c], s);
}

// ---------------- M[b] = Ks_b^T Cur_b -> MT[d][i] (bf16)  [MFMA] ----------------
__global__ __launch_bounds__(256) void k_M(const unsigned short* __restrict__ ksT,
      const unsigned short* __restrict__ curT, unsigned short* __restrict__ MT, int N, int PG){
  int b = blockIdx.y;
  int wv = threadIdx.x >> 6, l = threadIdx.x & 63;
  int gw = blockIdx.x * 4 + wv;
  int itile = gw & 7, jh = gw >> 3;
  int quad = l >> 4, lcol = l & 15;
  ffrag acc[4] = {};
  const unsigned short* Arow = ksT + (size_t)(itile * 16 + lcol) * N + (size_t)b * PG + quad * 8;
  const unsigned short* B0 = curT + (size_t)b * PG + quad * 8;
  int steps = PG / 32;
  for (int s = 0; s < steps; s++){
    bfrag a = *(const bfrag*)(Arow + s * 32);
#pragma unroll
    for (int jt = 0; jt < 4; jt++){
      bfrag bb = *(const bfrag*)(B0 + (size_t)((jh * 4 + jt) * 16 + lcol) * N + s * 32);
      acc[jt] = __builtin_amdgcn_mfma_f32_16x16x32_bf16(a, bb, acc[jt], 0, 0, 0);
    }
  }
  unsigned short* MTb = MT + (size_t)b * C * C;
  int i0 = itile * 16 + quad * 4;
#pragma unroll
  for (int jt = 0; jt < 4; jt++){
    int j = (jh * 4 + jt) * 16 + lcol;
    ushort4 pk;
    pk.x = f2bf(acc[jt][0]); pk.y = f2bf(acc[jt][1]);
    pk.z = f2bf(acc[jt][2]); pk.w = f2bf(acc[jt][3]);
    *(ushort4*)(MTb + (size_t)j * C + i0) = pk;
  }
}

// ---------------- GCN gather (CSR, packed edges), 4-edge unrolled ----------------
__global__ __launch_bounds__(256) void k_gcn(const int* __restrict__ row_ptr,
                      const int2* __restrict__ edge_s,
                      const unsigned int* __restrict__ cur32,
                      unsigned int* __restrict__ gcn32, int N){
  int nid = blockIdx.x * 4 + (threadIdx.x >> 6);
  int c = threadIdx.x & 63;                 // channel-pair index
  if (nid >= N) return;
  int s = row_ptr[nid], e = row_ptr[nid + 1];
  float a0 = 0.f, a1 = 0.f;
  int p = s;
  for (; p + 4 <= e; p += 4){
    int2 e0 = edge_s[p],     e1 = edge_s[p + 1];
    int2 e2 = edge_s[p + 2], e3 = edge_s[p + 3];
    float f0 = __int_as_float(e0.y), f1 = __int_as_float(e1.y);
    float f2 = __int_as_float(e2.y), f3 = __int_as_float(e3.y);
    unsigned int u0 = cur32[(size_t)e0.x * 64 + c];
    unsigned int u1 = cur32[(size_t)e1.x * 64 + c];
    unsigned int u2 = cur32[(size_t)e2.x * 64 + c];
    unsigned int u3 = cur32[(size_t)e3.x * 64 + c];
    a0 += f0 * bf2f((unsigned short)(u0 & 0xffffu));
    a1 += f0 * bf2f((unsigned short)(u0 >> 16));
    a0 += f1 * bf2f((unsigned short)(u1 & 0xffffu));
    a1 += f1 * bf2f((unsigned short)(u1 >> 16));
    a0 += f2 * bf2f((unsigned short)(u2 & 0xffffu));
    a1 += f2 * bf2f((unsigned short)(u2 >> 16));
    a0 += f3 * bf2f((unsigned short)(u3 & 0xffffu));
    a1 += f3 * bf2f((unsigned short)(u3 >> 16));
  }
  for (; p < e; p++){
    int2 ed = edge_s[p];
    float cf = __int_as_float(ed.y);
    unsigned int u = cur32[(size_t)ed.x * 64 + c];
    a0 += cf * bf2f((unsigned short)(u & 0xffffu));
    a1 += cf * bf2f((unsigned short)(u >> 16));
  }
  gcn32[(size_t)nid * 64 + c] = ((unsigned int)f2bf(a1) << 16) | (unsigned int)f2bf(a0);
}

// ---------------- phase2 [MFMA]; also folds next-iteration vsum ----------------
__global__ __launch_bounds__(256) void k_phase2(const unsigned short* __restrict__ qs,
      const unsigned short* __restrict__ MT, const float* __restrict__ vsum,
      const float* __restrict__ denom, const unsigned short* __restrict__ gcn16,
      unsigned short* __restrict__ cur16, unsigned short* __restrict__ curT,
      float* __restrict__ accf, unsigned short* __restrict__ acc16,
      float* __restrict__ vsumN,           // next-iter vsum accumulator (nullptr on last)
      int N, int PG, int last){
  int wv = threadIdx.x >> 6, l = threadIdx.x & 63;
  int m0 = (blockIdx.x * 4 + wv) * 16;
  if (m0 >= N) return;
  int b = m0 / PG;
  int quad = l >> 4, lcol = l & 15;
  ffrag acc[8] = {};
  const unsigned short* Abase = qs + (size_t)(m0 + lcol) * C + quad * 8;
  const unsigned short* MTb = MT + (size_t)b * C * C;
#pragma unroll
  for (int s = 0; s < 4; s++){
    bfrag a = *(const bfrag*)(Abase + s * 32);
#pragma unroll
    for (int dt = 0; dt < 8; dt++){
      bfrag bb = *(const bfrag*)(MTb + (size_t)(dt * 16 + lcol) * C + s * 32 + quad * 8);
      acc[dt] = __builtin_amdgcn_mfma_f32_16x16x32_bf16(a, bb, acc[dt], 0, 0, 0);
    }
  }
  float dn[4];
#pragma unroll
  for (int r = 0; r < 4; r++) dn[r] = denom[m0 + quad * 4 + r];
#pragma unroll
  for (int dt = 0; dt < 8; dt++){
    int d = dt * 16 + lcol;
    float vs = vsum[b * C + d];
    ushort4 pk;
    float vnext = 0.f;
#pragma unroll
    for (int r = 0; r < 4; r++){
      int m = m0 + quad * 4 + r;
      float attn = (acc[dt][r] + vs) / dn[r];
      float g = bf2f(gcn16[(size_t)m * C + d]);
      float nc = 0.5f * (g + attn);           // BETA = 0.5
      float na = accf[(size_t)m * C + d] + nc;
      accf[(size_t)m * C + d] = na;
      unsigned short nb = f2bf(nc);
      cur16[(size_t)m * C + d] = nb;
      if (last) acc16[(size_t)m * C + d] = f2bf(na);
      ((unsigned short*)&pk)[r] = nb;
      vnext += bf2f(nb);
    }
    *(ushort4*)(curT + (size_t)d * N + m0 + quad * 4) = pk;
    if (vsumN){
      vnext += __shfl_xor(vnext, 16, 64);
      vnext += __shfl_xor(vnext, 32, 64);
      if (quad == 0) atomicAdd(&vsumN[b * C + d], vnext);
    }
  }
}

// ---------------- out = acc @ Wo^T + Wo_b  (FP32 OUTPUT)  [MFMA] ----------------
__global__ __launch_bounds__(256) void k_final(const unsigned short* __restrict__ acc16,
      const unsigned short* __restrict__ Wo, const float* __restrict__ Wob,
      float* __restrict__ out, int N){
  int wv = threadIdx.x >> 6, l = threadIdx.x & 63;
  int m0 = (blockIdx.x * 4 + wv) * 16;
  if (m0 >= N) return;
  int quad = l >> 4, lcol = l & 15;
  ffrag acc[8] = {};
  const unsigned short* Abase = acc16 + (size_t)(m0 + lcol) * C + quad * 8;
#pragma unroll
  for (int s = 0; s < 4; s++){
    bfrag a = *(const bfrag*)(Abase + s * 32);
#pragma unroll
    for (int ot = 0; ot < 8; ot++){
      bfrag bb = *(const bfrag*)(Wo + (size_t)(ot * 16 + lcol) * C + s * 32 + quad * 8);
      acc[ot] = __builtin_amdgcn_mfma_f32_16x16x32_bf16(a, bb, acc[ot], 0, 0, 0);
    }
  }
#pragma unroll
  for (int ot = 0; ot < 8; ot++){
    float bias = Wob[ot * 16 + lcol];
#pragma unroll
    for (int r = 0; r < 4; r++){
      out[(size_t)(m0 + quad * 4 + r) * C + ot * 16 + lcol] = acc[ot][r] + bias;   // fp32 store
    }
  }
}

// ================= host =================

extern "C" void kernel_launch(void* const* d_in, const int* in_sizes, int n_in,
                              void* d_out, int out_size, void* d_ws, size_t ws_size,
                              hipStream_t stream){
  const float* x    = (const float*)d_in[0];
  const int*   eidx = (const int*)d_in[1];
  const float* ew   = (const float*)d_in[2];
  const int*   n_nodes = (const int*)d_in[3];
  const float* Wq_w = (const float*)d_in[4];
  const float* Wq_b = (const float*)d_in[5];
  const float* Wk_w = (const float*)d_in[6];
  const float* Wk_b = (const float*)d_in[7];
  const float* Wo_w = (const float*)d_in[8];
  const float* Wo_b = (const float*)d_in[9];
  float* out = (float*)d_out;                  // fp32 output

  int N = in_sizes[0] / C;
  int E = in_sizes[2];
  int B = in_sizes[3];
  int PG = N / B;
  const int* row = eidx;
  const int* col = eidx + E;

  char* p = (char*)d_ws;
  auto alloc = [&](size_t bytes) -> void* {
    void* r = (void*)p; p += (bytes + 255) & ~(size_t)255; return r;
  };
  unsigned short* cur16 = (unsigned short*)alloc((size_t)N * C * 2);
  unsigned short* curT  = (unsigned short*)alloc((size_t)N * C * 2);
  unsigned short* qs16  = (unsigned short*)alloc((size_t)N * C * 2);
  unsigned short* ksT   = (unsigned short*)alloc((size_t)N * C * 2);
  unsigned short* gcn16 = (unsigned short*)alloc((size_t)N * C * 2);
  unsigned short* acc16 = (unsigned short*)alloc((size_t)N * C * 2);
  float*          accf  = (float*)alloc((size_t)N * C * 4);
  unsigned short* MT    = (unsigned short*)alloc((size_t)B * C * C * 2);
  unsigned short* Wq16  = (unsigned short*)alloc((size_t)C * C * 2);
  unsigned short* Wk16  = (unsigned short*)alloc((size_t)C * C * 2);
  unsigned short* Wo16  = (unsigned short*)alloc((size_t)C * C * 2);
  unsigned long long* deg64 = (unsigned long long*)alloc((size_t)N * 8);
  float*          dinv  = (float*)alloc((size_t)N * 4);
  int*            cnt   = (int*)alloc((size_t)N * 4);
  int*            row_ptr = (int*)alloc((size_t)(N + 1) * 4);
  int*            rank  = (int*)alloc((size_t)E * 4);
  int*            bsum  = (int*)alloc(1024);
  int*            bbase = (int*)alloc(1024);
  int2*           edge_s = (int2*)alloc((size_t)E * 8);
  float*          ksum  = (float*)alloc((size_t)B * C * 4);
  float*          vsumA = (float*)alloc((size_t)B * C * 4);
  float*          vsumB = (float*)alloc((size_t)B * C * 4);
  float*          denom = (float*)alloc((size_t)N * 4);

  dim3 b256(256);
  int wblocks = (N / 16 + 3) / 4;   // one wave per 16 nodes, 4 waves/block
  int WW = C * C;
  int nscan = (N + 255) / 256;

  // loop-invariant prep
  k_zero<<<dim3((2 * N + 255) / 256), b256, 0, stream>>>((float*)nullptr, (int*)deg64, 2 * N);
  k_zero<<<dim3((B * C + 255) / 256), b256, 0, stream>>>(ksum, (int*)nullptr, B * C);
  k_zero<<<dim3((B * C + 255) / 256), b256, 0, stream>>>(vsumA, (int*)nullptr, B * C);
  k_degcnt<<<dim3((E + 255) / 256), b256, 0, stream>>>(row, ew, deg64, rank, E);
  k_decode<<<dim3((N + 255) / 256), b256, 0, stream>>>(deg64, dinv, cnt, N);
  k_scan1<<<dim3(nscan), b256, 0, stream>>>(cnt, bsum, N);
  k_scan2<<<1, b256, 0, stream>>>(bsum, bbase, nscan);
  k_scan3<<<dim3(nscan), b256, 0, stream>>>(cnt, bbase, row_ptr, N);
  k_fill<<<dim3((E + 255) / 256), b256, 0, stream>>>(row, col, ew, rank, row_ptr, dinv, edge_s, E);
  k_init<<<dim3((N * C + 255) / 256), b256, 0, stream>>>(x, cur16, accf, N * C);
  k_cast<<<dim3((WW + 255) / 256), b256, 0, stream>>>(Wq_w, Wq16, WW);
  k_cast<<<dim3((WW + 255) / 256), b256, 0, stream>>>(Wk_w, Wk16, WW);
  k_cast<<<dim3((WW + 255) / 256), b256, 0, stream>>>(Wo_w, Wo16, WW);
  k_transpose<<<dim3(N / 64, C / 64), b256, 0, stream>>>(cur16, curT, N);
  k_proj<<<dim3(wblocks), b256, 0, stream>>>(cur16, Wq16, Wq_b, qs16, (float*)nullptr, N, PG, 0);
  k_proj<<<dim3(wblocks), b256, 0, stream>>>(cur16, Wk16, Wk_b, ksT, ksum, N, PG, 1);
  k_denom<<<dim3((N + 3) / 4), b256, 0, stream>>>(qs16, ksum, n_nodes, denom, N, PG);
  k_vsum<<<dim3(B, 8), dim3(C), 0, stream>>>(cur16, vsumA, PG);   // vsum of bf16(x)

  // 4 propagation iterations (vsum ping-pong; phase2 folds next-iter vsum)
  float* vs_cur = vsumA;
  float* vs_nxt = vsumB;
  for (int it = 0; it < 4; it++){
    int last = (it == 3);
    if (!last)
      k_zero<<<dim3((B * C + 255) / 256), b256, 0, stream>>>(vs_nxt, (int*)nullptr, B * C);
    k_M<<<dim3(4, B), b256, 0, stream>>>(ksT, curT, MT, N, PG);
    k_gcn<<<dim3((N + 3) / 4), b256, 0, stream>>>(row_ptr, edge_s,
                                                  (const unsigned int*)cur16,
                                                  (unsigned int*)gcn16, N);
    k_phase2<<<dim3(wblocks), b256, 0, stream>>>(qs16, MT, vs_cur, denom, gcn16,
                                                 cur16, curT, accf, acc16,
                                                 last ? (float*)nullptr : vs_nxt,
                                                 N, PG, last);
    float* tmp = vs_cur; vs_cur = vs_nxt; vs_nxt = tmp;
  }

  k_final<<<dim3(wblocks), b256, 0, stream>>>(acc16, Wo16, Wo_b, out, N);
}

// Round 3
// 416.768 us; speedup vs baseline: 1.2772x; 1.1634x over previous
//
#include <hip/hip_runtime.h>
#include <stdint.h>

#define C 128

typedef __attribute__((ext_vector_type(8))) short bfrag;   // 8 x bf16 (4 VGPRs)
typedef __attribute__((ext_vector_type(4))) float ffrag;   // 4 x f32 accum

__device__ __forceinline__ unsigned short f2bf(float f){
  union { float f; unsigned int i; } v; v.f = f;
  unsigned int x = v.i;
  unsigned int r = x + 0x7fffu + ((x >> 16) & 1u);   // round-to-nearest-even
  return (unsigned short)(r >> 16);
}
__device__ __forceinline__ float bf2f(unsigned short u){
  union { unsigned int i; float f; } v; v.i = ((unsigned int)u) << 16; return v.f;
}

// ---------------- zero one contiguous region (deg64 | ksum | vsumA) ----------------
__global__ void k_zero_region(unsigned int* base, int nwords){
  int i = blockIdx.x * 256 + threadIdx.x;
  if (i < nwords) base[i] = 0u;
}

// ---------------- merged: deg/cnt atomics + weight casts ----------------
// deg64: high 32 = count, low 32 = weight in 24-bit fixed point; atomic return = rank.
__global__ void k_degcast(const int* __restrict__ row, const float* __restrict__ w,
                          unsigned long long* deg64, int* __restrict__ rank, int E,
                          const float* __restrict__ Wq, const float* __restrict__ Wk,
                          const float* __restrict__ Wo, unsigned short* __restrict__ W16,
                          int WW, int degB){
  int bx = blockIdx.x;
  if (bx < degB){
    int e = bx * 256 + threadIdx.x;
    if (e < E){
      int r = row[e];
      unsigned int wf = (unsigned int)(w[e] * 16777216.0f + 0.5f);   // w * 2^24
      unsigned long long old =
          atomicAdd(&deg64[r], 0x100000000ULL | (unsigned long long)wf);
      rank[e] = (int)(old >> 32);
    }
  } else {
    int i = (bx - degB) * 256 + threadIdx.x;
    if (i < 3 * WW){
      const float* src = (i < WW) ? Wq : ((i < 2 * WW) ? Wk : Wo);
      int off = (i < WW) ? 0 : ((i < 2 * WW) ? WW : 2 * WW);
      W16[i] = f2bf(src[i - off]);
    }
  }
}

// ---- scan stage 1: per-block sums of cnt (decoded from deg64) + dinv decode ----
__global__ void k_scan1(const unsigned long long* __restrict__ deg64,
                        float* __restrict__ dinv, int* bsum, int N){
  __shared__ int s[256];
  int b = blockIdx.x, t = threadIdx.x;
  int i = b * 256 + t;
  int cnt = 0;
  if (i < N){
    unsigned long long v = deg64[i];
    cnt = (int)(v >> 32);
    unsigned int lo = (unsigned int)v;
    float d = (float)lo * (1.0f / 16777216.0f);
    dinv[i] = lo > 0u ? 1.0f / sqrtf(d) : 0.f;
  }
  s[t] = cnt;
  __syncthreads();
  for (int o = 128; o; o >>= 1){ if (t < o) s[t] += s[t + o]; __syncthreads(); }
  if (t == 0) bsum[b] = s[0];
}

// ---- scan stage 2: each block sums bsum[0..b) itself, then local inclusive scan ----
__global__ void k_scan3(const unsigned long long* __restrict__ deg64,
                        const int* __restrict__ bsum, int* row_ptr, int N){
  __shared__ int s[256];
  int b = blockIdx.x, t = threadIdx.x;
  int i = b * 256 + t;
  int v = (i < N) ? (int)(deg64[i] >> 32) : 0;
  s[t] = v;
  __syncthreads();
  for (int o = 1; o < 256; o <<= 1){
    int u = (t >= o) ? s[t - o] : 0;
    __syncthreads(); s[t] += u; __syncthreads();
  }
  int base = 0;
  for (int j = 0; j < b; j++) base += bsum[j];
  int excl = base + s[t] - v;
  if (i < N) row_ptr[i] = excl;
  if (i == N - 1) row_ptr[N] = excl + v;
}

// ---------------- merged: CSR fill + (x -> cur16/curT/accf/vsum) prep ----------------
__global__ __launch_bounds__(256) void k_fillprep(
    const int* __restrict__ row, const int* __restrict__ col,
    const float* __restrict__ w, const int* __restrict__ rank,
    const int* __restrict__ row_ptr, const float* __restrict__ dinv,
    int2* __restrict__ edge_s, int E, int fillB,
    const float* __restrict__ x, unsigned short* __restrict__ cur16,
    unsigned short* __restrict__ curT, float* __restrict__ accf,
    float* __restrict__ vsum, int N, int PG){
  __shared__ unsigned short tile[64][66];
  __shared__ float ssum[4][64];
  int bx = blockIdx.x;
  if (bx < fillB){
    int e = bx * 256 + threadIdx.x;
    if (e < E){
      int r = row[e], c = col[e];
      int p = row_ptr[r] + rank[e];
      float cf = dinv[r] * dinv[c] * w[e];
      int2 ed; ed.x = c; ed.y = __float_as_int(cf);
      edge_s[p] = ed;
    }
    return;
  }
  int pb = bx - fillB;
  int ntiles = N >> 6;
  int n0 = (pb % ntiles) * 64;
  int c0 = (pb / ntiles) * 64;
  int tx = threadIdx.x & 63, ty = threadIdx.x >> 6;
  int b = n0 / PG;                      // PG is a multiple of 64
  for (int r = ty; r < 64; r += 4){
    float v = x[(size_t)(n0 + r) * C + c0 + tx];
    accf[(size_t)(n0 + r) * C + c0 + tx] = v;
    unsigned short u = f2bf(v);
    cur16[(size_t)(n0 + r) * C + c0 + tx] = u;
    tile[r][tx] = u;
  }
  __syncthreads();
  for (int r = ty; r < 64; r += 4)
    curT[(size_t)(c0 + r) * N + n0 + tx] = tile[tx][r];
  float ps = 0.f;
  for (int r = ty * 16; r < ty * 16 + 16; r++) ps += bf2f(tile[r][tx]);
  ssum[ty][tx] = ps;
  __syncthreads();
  if (ty == 0){
    float s2 = ssum[0][tx] + ssum[1][tx] + ssum[2][tx] + ssum[3][tx];
    atomicAdd(&vsum[b * C + c0 + tx], s2);
  }
}

// ---------------- both projections in one launch [MFMA] ----------------
__global__ __launch_bounds__(256) void k_proj2(const unsigned short* __restrict__ x,
      const unsigned short* __restrict__ W16,
      const float* __restrict__ Wq_b, const float* __restrict__ Wk_b,
      unsigned short* __restrict__ qs, unsigned short* __restrict__ ksT,
      float* __restrict__ ksum, int N, int PG, int wblocks){
  int bx = blockIdx.x;
  int transposed = bx >= wblocks;
  int lb = transposed ? bx - wblocks : bx;
  const unsigned short* W = transposed ? (W16 + C * C) : W16;
  const float* Wb = transposed ? Wk_b : Wq_b;
  unsigned short* out = transposed ? ksT : qs;

  int wv = threadIdx.x >> 6, l = threadIdx.x & 63;
  int m0 = (lb * 4 + wv) * 16;
  if (m0 >= N) return;
  int quad = l >> 4, lcol = l & 15;
  ffrag acc[8] = {};
  const unsigned short* Abase = x + (size_t)(m0 + lcol) * C + quad * 8;
#pragma unroll
  for (int s = 0; s < 4; s++){
    bfrag a = *(const bfrag*)(Abase + s * 32);
#pragma unroll
    for (int nt = 0; nt < 8; nt++){
      bfrag bb = *(const bfrag*)(W + (size_t)(nt * 16 + lcol) * C + s * 32 + quad * 8);
      acc[nt] = __builtin_amdgcn_mfma_f32_16x16x32_bf16(a, bb, acc[nt], 0, 0, 0);
    }
  }
  float q[8][4];
  float ss[4] = {0.f, 0.f, 0.f, 0.f};
#pragma unroll
  for (int nt = 0; nt < 8; nt++){
    float bias = Wb[nt * 16 + lcol];
#pragma unroll
    for (int r = 0; r < 4; r++){ float v = acc[nt][r] + bias; q[nt][r] = v; ss[r] += v * v; }
  }
#pragma unroll
  for (int off = 1; off < 16; off <<= 1){
#pragma unroll
    for (int r = 0; r < 4; r++) ss[r] += __shfl_xor(ss[r], off, 64);
  }
  float inv[4];
#pragma unroll
  for (int r = 0; r < 4; r++) inv[r] = 1.0f / sqrtf(fmaxf(ss[r], 1e-30f));
  if (!transposed){
#pragma unroll
    for (int nt = 0; nt < 8; nt++)
#pragma unroll
      for (int r = 0; r < 4; r++)
        out[(size_t)(m0 + quad * 4 + r) * C + nt * 16 + lcol] = f2bf(q[nt][r] * inv[r]);
  } else {
    int b = m0 / PG;
#pragma unroll
    for (int nt = 0; nt < 8; nt++){
      ushort4 pk;
      float v0 = q[nt][0] * inv[0], v1 = q[nt][1] * inv[1];
      float v2 = q[nt][2] * inv[2], v3 = q[nt][3] * inv[3];
      pk.x = f2bf(v0); pk.y = f2bf(v1); pk.z = f2bf(v2); pk.w = f2bf(v3);
      *(ushort4*)(out + (size_t)(nt * 16 + lcol) * N + m0 + quad * 4) = pk;
      float s = v0 + v1 + v2 + v3;
      s += __shfl_xor(s, 16, 64);
      s += __shfl_xor(s, 32, 64);
      if (quad == 0) atomicAdd(&ksum[b * C + nt * 16 + lcol], s);
    }
  }
}

__global__ void k_denom(const unsigned short* __restrict__ qs, const float* __restrict__ ksum,
                        const int* __restrict__ n_nodes, float* denom, int N, int PG){
  int wv = threadIdx.x >> 6, l = threadIdx.x & 63;
  int m = blockIdx.x * 4 + wv;
  if (m >= N) return;
  int b = m / PG;
  float s = bf2f(qs[(size_t)m * C + l]) * ksum[b * C + l]
          + bf2f(qs[(size_t)m * C + 64 + l]) * ksum[b * C + 64 + l];
#pragma unroll
  for (int off = 32; off; off >>= 1) s += __shfl_xor(s, off, 64);
  if (l == 0) denom[m] = s + (float)n_nodes[b];
}

// ---------------- merged per-iteration mid kernel ----------------
// blocks [0, mB):          M[b] = Ks_b^T Cur_b  (MFMA, compute-heavy, dispatched first)
// blocks [mB, mB+gcnB):    GCN CSR gather
// blocks [mB+gcnB, ...):   zero vsumN for next iteration
__global__ __launch_bounds__(256) void k_mid(const unsigned short* __restrict__ ksT,
      const unsigned short* __restrict__ curT, unsigned short* __restrict__ MT,
      const int* __restrict__ row_ptr, const int2* __restrict__ edge_s,
      const unsigned int* __restrict__ cur32, unsigned int* __restrict__ gcn32,
      float* __restrict__ vsumN, int N, int PG, int BC, int mB, int gcnB){
  int bx = blockIdx.x;
  if (bx < mB){
    int wv = threadIdx.x >> 6, l = threadIdx.x & 63;
    int b = bx >> 2;
    int gw = (bx & 3) * 4 + wv;
    int itile = gw & 7, jh = gw >> 3;
    int quad = l >> 4, lcol = l & 15;
    ffrag acc[4] = {};
    const unsigned short* Arow = ksT + (size_t)(itile * 16 + lcol) * N + (size_t)b * PG + quad * 8;
    const unsigned short* B0 = curT + (size_t)b * PG + quad * 8;
    int steps = PG / 32;
    for (int s = 0; s < steps; s++){
      bfrag a = *(const bfrag*)(Arow + s * 32);
#pragma unroll
      for (int jt = 0; jt < 4; jt++){
        bfrag bb = *(const bfrag*)(B0 + (size_t)((jh * 4 + jt) * 16 + lcol) * N + s * 32);
        acc[jt] = __builtin_amdgcn_mfma_f32_16x16x32_bf16(a, bb, acc[jt], 0, 0, 0);
      }
    }
    unsigned short* MTb = MT + (size_t)b * C * C;
    int i0 = itile * 16 + quad * 4;
#pragma unroll
    for (int jt = 0; jt < 4; jt++){
      int j = (jh * 4 + jt) * 16 + lcol;
      ushort4 pk;
      pk.x = f2bf(acc[jt][0]); pk.y = f2bf(acc[jt][1]);
      pk.z = f2bf(acc[jt][2]); pk.w = f2bf(acc[jt][3]);
      *(ushort4*)(MTb + (size_t)j * C + i0) = pk;
    }
    return;
  }
  bx -= mB;
  if (bx < gcnB){
    int nid = bx * 4 + (threadIdx.x >> 6);
    int c = threadIdx.x & 63;                 // channel-pair index
    if (nid >= N) return;
    int s = row_ptr[nid], e = row_ptr[nid + 1];
    float a0 = 0.f, a1 = 0.f;
    int p = s;
    for (; p + 4 <= e; p += 4){
      int2 e0 = edge_s[p],     e1 = edge_s[p + 1];
      int2 e2 = edge_s[p + 2], e3 = edge_s[p + 3];
      float f0 = __int_as_float(e0.y), f1 = __int_as_float(e1.y);
      float f2 = __int_as_float(e2.y), f3 = __int_as_float(e3.y);
      unsigned int u0 = cur32[(size_t)e0.x * 64 + c];
      unsigned int u1 = cur32[(size_t)e1.x * 64 + c];
      unsigned int u2 = cur32[(size_t)e2.x * 64 + c];
      unsigned int u3 = cur32[(size_t)e3.x * 64 + c];
      a0 += f0 * bf2f((unsigned short)(u0 & 0xffffu));
      a1 += f0 * bf2f((unsigned short)(u0 >> 16));
      a0 += f1 * bf2f((unsigned short)(u1 & 0xffffu));
      a1 += f1 * bf2f((unsigned short)(u1 >> 16));
      a0 += f2 * bf2f((unsigned short)(u2 & 0xffffu));
      a1 += f2 * bf2f((unsigned short)(u2 >> 16));
      a0 += f3 * bf2f((unsigned short)(u3 & 0xffffu));
      a1 += f3 * bf2f((unsigned short)(u3 >> 16));
    }
    for (; p < e; p++){
      int2 ed = edge_s[p];
      float cf = __int_as_float(ed.y);
      unsigned int u = cur32[(size_t)ed.x * 64 + c];
      a0 += cf * bf2f((unsigned short)(u & 0xffffu));
      a1 += cf * bf2f((unsigned short)(u >> 16));
    }
    gcn32[(size_t)nid * 64 + c] = ((unsigned int)f2bf(a1) << 16) | (unsigned int)f2bf(a0);
    return;
  }
  bx -= gcnB;
  if (vsumN){
    int idx = bx * 256 + threadIdx.x;
    if (idx < BC) vsumN[idx] = 0.f;
  }
}

// ---------------- phase2 [MFMA]; also folds next-iteration vsum ----------------
__global__ __launch_bounds__(256) void k_phase2(const unsigned short* __restrict__ qs,
      const unsigned short* __restrict__ MT, const float* __restrict__ vsum,
      const float* __restrict__ denom, const unsigned short* __restrict__ gcn16,
      unsigned short* __restrict__ cur16, unsigned short* __restrict__ curT,
      float* __restrict__ accf, unsigned short* __restrict__ acc16,
      float* __restrict__ vsumN,           // next-iter vsum accumulator (nullptr on last)
      int N, int PG, int last){
  int wv = threadIdx.x >> 6, l = threadIdx.x & 63;
  int m0 = (blockIdx.x * 4 + wv) * 16;
  if (m0 >= N) return;
  int b = m0 / PG;
  int quad = l >> 4, lcol = l & 15;
  ffrag acc[8] = {};
  const unsigned short* Abase = qs + (size_t)(m0 + lcol) * C + quad * 8;
  const unsigned short* MTb = MT + (size_t)b * C * C;
#pragma unroll
  for (int s = 0; s < 4; s++){
    bfrag a = *(const bfrag*)(Abase + s * 32);
#pragma unroll
    for (int dt = 0; dt < 8; dt++){
      bfrag bb = *(const bfrag*)(MTb + (size_t)(dt * 16 + lcol) * C + s * 32 + quad * 8);
      acc[dt] = __builtin_amdgcn_mfma_f32_16x16x32_bf16(a, bb, acc[dt], 0, 0, 0);
    }
  }
  float dn[4];
#pragma unroll
  for (int r = 0; r < 4; r++) dn[r] = denom[m0 + quad * 4 + r];
#pragma unroll
  for (int dt = 0; dt < 8; dt++){
    int d = dt * 16 + lcol;
    float vs = vsum[b * C + d];
    ushort4 pk;
    float vnext = 0.f;
#pragma unroll
    for (int r = 0; r < 4; r++){
      int m = m0 + quad * 4 + r;
      float attn = (acc[dt][r] + vs) / dn[r];
      float g = bf2f(gcn16[(size_t)m * C + d]);
      float nc = 0.5f * (g + attn);           // BETA = 0.5
      float na = accf[(size_t)m * C + d] + nc;
      accf[(size_t)m * C + d] = na;
      unsigned short nb = f2bf(nc);
      cur16[(size_t)m * C + d] = nb;
      if (last) acc16[(size_t)m * C + d] = f2bf(na);
      ((unsigned short*)&pk)[r] = nb;
      vnext += bf2f(nb);
    }
    *(ushort4*)(curT + (size_t)d * N + m0 + quad * 4) = pk;
    if (vsumN){
      vnext += __shfl_xor(vnext, 16, 64);
      vnext += __shfl_xor(vnext, 32, 64);
      if (quad == 0) atomicAdd(&vsumN[b * C + d], vnext);
    }
  }
}

// ---------------- out = acc @ Wo^T + Wo_b  (FP32 OUTPUT)  [MFMA] ----------------
__global__ __launch_bounds__(256) void k_final(const unsigned short* __restrict__ acc16,
      const unsigned short* __restrict__ Wo, const float* __restrict__ Wob,
      float* __restrict__ out, int N){
  int wv = threadIdx.x >> 6, l = threadIdx.x & 63;
  int m0 = (blockIdx.x * 4 + wv) * 16;
  if (m0 >= N) return;
  int quad = l >> 4, lcol = l & 15;
  ffrag acc[8] = {};
  const unsigned short* Abase = acc16 + (size_t)(m0 + lcol) * C + quad * 8;
#pragma unroll
  for (int s = 0; s < 4; s++){
    bfrag a = *(const bfrag*)(Abase + s * 32);
#pragma unroll
    for (int ot = 0; ot < 8; ot++){
      bfrag bb = *(const bfrag*)(Wo + (size_t)(ot * 16 + lcol) * C + s * 32 + quad * 8);
      acc[ot] = __builtin_amdgcn_mfma_f32_16x16x32_bf16(a, bb, acc[ot], 0, 0, 0);
    }
  }
#pragma unroll
  for (int ot = 0; ot < 8; ot++){
    float bias = Wob[ot * 16 + lcol];
#pragma unroll
    for (int r = 0; r < 4; r++){
      out[(size_t)(m0 + quad * 4 + r) * C + ot * 16 + lcol] = acc[ot][r] + bias;   // fp32 store
    }
  }
}

// ================= host =================

extern "C" void kernel_launch(void* const* d_in, const int* in_sizes, int n_in,
                              void* d_out, int out_size, void* d_ws, size_t ws_size,
                              hipStream_t stream){
  const float* x    = (const float*)d_in[0];
  const int*   eidx = (const int*)d_in[1];
  const float* ew   = (const float*)d_in[2];
  const int*   n_nodes = (const int*)d_in[3];
  const float* Wq_w = (const float*)d_in[4];
  const float* Wq_b = (const float*)d_in[5];
  const float* Wk_w = (const float*)d_in[6];
  const float* Wk_b = (const float*)d_in[7];
  const float* Wo_w = (const float*)d_in[8];
  const float* Wo_b = (const float*)d_in[9];
  float* out = (float*)d_out;                  // fp32 output

  int N = in_sizes[0] / C;
  int E = in_sizes[2];
  int B = in_sizes[3];
  int PG = N / B;
  int BC = B * C;
  const int* row = eidx;
  const int* col = eidx + E;

  char* p = (char*)d_ws;
  auto alloc = [&](size_t bytes) -> void* {
    void* r = (void*)p; p += (bytes + 255) & ~(size_t)255; return r;
  };
  unsigned short* cur16 = (unsigned short*)alloc((size_t)N * C * 2);
  unsigned short* curT  = (unsigned short*)alloc((size_t)N * C * 2);
  unsigned short* qs16  = (unsigned short*)alloc((size_t)N * C * 2);
  unsigned short* ksT   = (unsigned short*)alloc((size_t)N * C * 2);
  unsigned short* gcn16 = (unsigned short*)alloc((size_t)N * C * 2);
  unsigned short* acc16 = (unsigned short*)alloc((size_t)N * C * 2);
  float*          accf  = (float*)alloc((size_t)N * C * 4);
  unsigned short* MT    = (unsigned short*)alloc((size_t)B * C * C * 2);
  unsigned short* W16   = (unsigned short*)alloc((size_t)3 * C * C * 2);  // Wq|Wk|Wo
  // contiguous zero region: deg64 (N u64) | ksum (BC f32) | vsumA (BC f32)
  char* zbase = (char*)alloc((size_t)N * 8 + (size_t)BC * 8);
  unsigned long long* deg64 = (unsigned long long*)zbase;
  float*          ksum  = (float*)(zbase + (size_t)N * 8);
  float*          vsumA = (float*)(zbase + (size_t)N * 8 + (size_t)BC * 4);
  float*          dinv  = (float*)alloc((size_t)N * 4);
  int*            row_ptr = (int*)alloc((size_t)(N + 1) * 4);
  int*            rank  = (int*)alloc((size_t)E * 4);
  int*            bsum  = (int*)alloc(1024);
  int2*           edge_s = (int2*)alloc((size_t)E * 8);
  float*          vsumB = (float*)alloc((size_t)BC * 4);
  float*          denom = (float*)alloc((size_t)N * 4);

  dim3 b256(256);
  int wblocks = (N / 16 + 3) / 4;   // one wave per 16 nodes, 4 waves/block
  int WW = C * C;
  int nscan = (N + 255) / 256;
  int degB = (E + 255) / 256;
  int castB = (3 * WW + 255) / 256;
  int fillB = (E + 255) / 256;
  int prepB = (N / 64) * (C / 64);
  int mB = 4 * B;
  int gcnB = (N + 3) / 4;
  int zvB = (BC + 255) / 256;
  int zwords = 2 * N + 2 * BC;      // deg64 + ksum + vsumA, as u32 words

  // ---- prep (7 launches) ----
  k_zero_region<<<dim3((zwords + 255) / 256), b256, 0, stream>>>((unsigned int*)deg64, zwords);
  k_degcast<<<dim3(degB + castB), b256, 0, stream>>>(row, ew, deg64, rank, E,
                                                     Wq_w, Wk_w, Wo_w, W16, WW, degB);
  k_scan1<<<dim3(nscan), b256, 0, stream>>>(deg64, dinv, bsum, N);
  k_scan3<<<dim3(nscan), b256, 0, stream>>>(deg64, bsum, row_ptr, N);
  k_fillprep<<<dim3(fillB + prepB), b256, 0, stream>>>(row, col, ew, rank, row_ptr, dinv,
                                                       edge_s, E, fillB,
                                                       x, cur16, curT, accf, vsumA, N, PG);
  k_proj2<<<dim3(2 * wblocks), b256, 0, stream>>>(cur16, W16, Wq_b, Wk_b,
                                                  qs16, ksT, ksum, N, PG, wblocks);
  k_denom<<<dim3((N + 3) / 4), b256, 0, stream>>>(qs16, ksum, n_nodes, denom, N, PG);

  // ---- 4 propagation iterations, 2 launches each ----
  float* vs_cur = vsumA;
  float* vs_nxt = vsumB;
  for (int it = 0; it < 4; it++){
    int last = (it == 3);
    k_mid<<<dim3(mB + gcnB + zvB), b256, 0, stream>>>(ksT, curT, MT, row_ptr, edge_s,
                                                      (const unsigned int*)cur16,
                                                      (unsigned int*)gcn16,
                                                      last ? (float*)nullptr : vs_nxt,
                                                      N, PG, BC, mB, gcnB);
    k_phase2<<<dim3(wblocks), b256, 0, stream>>>(qs16, MT, vs_cur, denom, gcn16,
                                                 cur16, curT, accf, acc16,
                                                 last ? (float*)nullptr : vs_nxt,
                                                 N, PG, last);
    float* tmp = vs_cur; vs_cur = vs_nxt; vs_nxt = tmp;
  }

  k_final<<<dim3(wblocks), b256, 0, stream>>>(acc16, W16 + 2 * WW, Wo_b, out, N);
}

// Round 4
// 385.997 us; speedup vs baseline: 1.3790x; 1.0797x over previous
//
#include <hip/hip_runtime.h>
#include <stdint.h>

#define C 128

typedef __attribute__((ext_vector_type(8))) short bfrag;   // 8 x bf16 (4 VGPRs)
typedef __attribute__((ext_vector_type(4))) float ffrag;   // 4 x f32 accum

__device__ __forceinline__ unsigned short f2bf(float f){
  union { float f; unsigned int i; } v; v.f = f;
  unsigned int x = v.i;
  unsigned int r = x + 0x7fffu + ((x >> 16) & 1u);   // round-to-nearest-even
  return (unsigned short)(r >> 16);
}
__device__ __forceinline__ float bf2f(unsigned short u){
  union { unsigned int i; float f; } v; v.i = ((unsigned int)u) << 16; return v.f;
}

// ---------------- zero deg64 ----------------
__global__ void k_zero_region(unsigned int* base, int nwords){
  int i = blockIdx.x * 256 + threadIdx.x;
  if (i < nwords) base[i] = 0u;
}

// ---------------- merged: deg/cnt atomics + weight casts ----------------
// deg64: high 32 = count, low 32 = weight in 24-bit fixed point; atomic return = rank.
__global__ void k_degcast(const int* __restrict__ row, const float* __restrict__ w,
                          unsigned long long* deg64, int* __restrict__ rank, int E,
                          const float* __restrict__ Wq, const float* __restrict__ Wk,
                          const float* __restrict__ Wo, unsigned short* __restrict__ W16,
                          int WW, int degB){
  int bx = blockIdx.x;
  if (bx < degB){
    int e = bx * 256 + threadIdx.x;
    if (e < E){
      int r = row[e];
      unsigned int wf = (unsigned int)(w[e] * 16777216.0f + 0.5f);   // w * 2^24
      unsigned long long old =
          atomicAdd(&deg64[r], 0x100000000ULL | (unsigned long long)wf);
      rank[e] = (int)(old >> 32);
    }
  } else {
    int i = (bx - degB) * 256 + threadIdx.x;
    if (i < 3 * WW){
      const float* src = (i < WW) ? Wq : ((i < 2 * WW) ? Wk : Wo);
      int off = (i < WW) ? 0 : ((i < 2 * WW) ? WW : 2 * WW);
      W16[i] = f2bf(src[i - off]);
    }
  }
}

// ---- scan stage 1: per-block sums of cnt (decoded from deg64) + dinv decode ----
__global__ void k_scan1(const unsigned long long* __restrict__ deg64,
                        float* __restrict__ dinv, int* bsum, int N){
  __shared__ int s[256];
  int b = blockIdx.x, t = threadIdx.x;
  int i = b * 256 + t;
  int cnt = 0;
  if (i < N){
    unsigned long long v = deg64[i];
    cnt = (int)(v >> 32);
    unsigned int lo = (unsigned int)v;
    float d = (float)lo * (1.0f / 16777216.0f);
    dinv[i] = lo > 0u ? 1.0f / sqrtf(d) : 0.f;
  }
  s[t] = cnt;
  __syncthreads();
  for (int o = 128; o; o >>= 1){ if (t < o) s[t] += s[t + o]; __syncthreads(); }
  if (t == 0) bsum[b] = s[0];
}

// ---- scan stage 2: each block sums bsum[0..b) itself, then local inclusive scan ----
__global__ void k_scan3(const unsigned long long* __restrict__ deg64,
                        const int* __restrict__ bsum, int* row_ptr, int N){
  __shared__ int s[256];
  int b = blockIdx.x, t = threadIdx.x;
  int i = b * 256 + t;
  int v = (i < N) ? (int)(deg64[i] >> 32) : 0;
  s[t] = v;
  __syncthreads();
  for (int o = 1; o < 256; o <<= 1){
    int u = (t >= o) ? s[t - o] : 0;
    __syncthreads(); s[t] += u; __syncthreads();
  }
  int base = 0;
  for (int j = 0; j < b; j++) base += bsum[j];
  int excl = base + s[t] - v;
  if (i < N) row_ptr[i] = excl;
  if (i == N - 1) row_ptr[N] = excl + v;
}

// ---------------- merged: CSR fill + (x -> cur0/curT) prep ----------------
__global__ __launch_bounds__(256) void k_fillprep(
    const int* __restrict__ row, const int* __restrict__ col,
    const float* __restrict__ w, const int* __restrict__ rank,
    const int* __restrict__ row_ptr, const float* __restrict__ dinv,
    int2* __restrict__ edge_s, int E, int fillB,
    const float* __restrict__ x, unsigned short* __restrict__ cur0,
    unsigned short* __restrict__ curT, int N){
  __shared__ unsigned short tile[64][66];
  int bx = blockIdx.x;
  if (bx < fillB){
    int e = bx * 256 + threadIdx.x;
    if (e < E){
      int r = row[e], c = col[e];
      int p = row_ptr[r] + rank[e];
      float cf = dinv[r] * dinv[c] * w[e];
      int2 ed; ed.x = c; ed.y = __float_as_int(cf);
      edge_s[p] = ed;
    }
    return;
  }
  int pb = bx - fillB;
  int ntiles = N >> 6;
  int n0 = (pb % ntiles) * 64;
  int c0 = (pb / ntiles) * 64;
  int tx = threadIdx.x & 63, ty = threadIdx.x >> 6;
  for (int r = ty; r < 64; r += 4){
    float v = x[(size_t)(n0 + r) * C + c0 + tx];
    unsigned short u = f2bf(v);
    cur0[(size_t)(n0 + r) * C + c0 + tx] = u;
    tile[r][tx] = u;
  }
  __syncthreads();
  for (int r = ty; r < 64; r += 4)
    curT[(size_t)(c0 + r) * N + n0 + tx] = tile[tx][r];
}

// ---------------- both projections in one launch [MFMA]; no atomics ----------------
__global__ __launch_bounds__(256) void k_proj2(const unsigned short* __restrict__ x,
      const unsigned short* __restrict__ W16,
      const float* __restrict__ Wq_b, const float* __restrict__ Wk_b,
      unsigned short* __restrict__ qs, unsigned short* __restrict__ ksT,
      int N, int wblocks){
  int bx = blockIdx.x;
  int transposed = bx >= wblocks;
  int lb = transposed ? bx - wblocks : bx;
  const unsigned short* W = transposed ? (W16 + C * C) : W16;
  const float* Wb = transposed ? Wk_b : Wq_b;
  unsigned short* out = transposed ? ksT : qs;

  int wv = threadIdx.x >> 6, l = threadIdx.x & 63;
  int m0 = (lb * 4 + wv) * 16;
  if (m0 >= N) return;
  int quad = l >> 4, lcol = l & 15;
  ffrag acc[8] = {};
  const unsigned short* Abase = x + (size_t)(m0 + lcol) * C + quad * 8;
#pragma unroll
  for (int s = 0; s < 4; s++){
    bfrag a = *(const bfrag*)(Abase + s * 32);
#pragma unroll
    for (int nt = 0; nt < 8; nt++){
      bfrag bb = *(const bfrag*)(W + (size_t)(nt * 16 + lcol) * C + s * 32 + quad * 8);
      acc[nt] = __builtin_amdgcn_mfma_f32_16x16x32_bf16(a, bb, acc[nt], 0, 0, 0);
    }
  }
  float q[8][4];
  float ss[4] = {0.f, 0.f, 0.f, 0.f};
#pragma unroll
  for (int nt = 0; nt < 8; nt++){
    float bias = Wb[nt * 16 + lcol];
#pragma unroll
    for (int r = 0; r < 4; r++){ float v = acc[nt][r] + bias; q[nt][r] = v; ss[r] += v * v; }
  }
#pragma unroll
  for (int off = 1; off < 16; off <<= 1){
#pragma unroll
    for (int r = 0; r < 4; r++) ss[r] += __shfl_xor(ss[r], off, 64);
  }
  float inv[4];
#pragma unroll
  for (int r = 0; r < 4; r++) inv[r] = 1.0f / sqrtf(fmaxf(ss[r], 1e-30f));
  if (!transposed){
#pragma unroll
    for (int nt = 0; nt < 8; nt++)
#pragma unroll
      for (int r = 0; r < 4; r++)
        out[(size_t)(m0 + quad * 4 + r) * C + nt * 16 + lcol] = f2bf(q[nt][r] * inv[r]);
  } else {
#pragma unroll
    for (int nt = 0; nt < 8; nt++){
      ushort4 pk;
      pk.x = f2bf(q[nt][0] * inv[0]); pk.y = f2bf(q[nt][1] * inv[1]);
      pk.z = f2bf(q[nt][2] * inv[2]); pk.w = f2bf(q[nt][3] * inv[3]);
      *(ushort4*)(out + (size_t)(nt * 16 + lcol) * N + m0 + quad * 4) = pk;
    }
  }
}

__global__ void k_denom(const unsigned short* __restrict__ qs, const float* __restrict__ ksum,
                        const int* __restrict__ n_nodes, float* denom, int N, int PG){
  int wv = threadIdx.x >> 6, l = threadIdx.x & 63;
  int m = blockIdx.x * 4 + wv;
  if (m >= N) return;
  int b = m / PG;
  float s = bf2f(qs[(size_t)m * C + l]) * ksum[b * C + l]
          + bf2f(qs[(size_t)m * C + 64 + l]) * ksum[b * C + 64 + l];
#pragma unroll
  for (int off = 32; off; off >>= 1) s += __shfl_xor(s, off, 64);
  if (l == 0) denom[m] = s + (float)n_nodes[b];
}

// ---------------- merged per-iteration mid kernel ----------------
// blocks [0, mB):                 M[b] = Ks_b^T Cur_b  (MFMA)
// blocks [mB, mB+vsB):            vsum[b][d] = sum_n curT[d][b*PG+n]  (direct write)
// blocks [mB+vsB, mB+vsB+ksB):    ksum[b][d] = sum_n ksT[d][b*PG+n]   (it0 only)
// rest:                           GCN CSR gather
__global__ __launch_bounds__(256) void k_mid(const unsigned short* __restrict__ ksT,
      const unsigned short* __restrict__ curT, unsigned short* __restrict__ MT,
      const int* __restrict__ row_ptr, const int2* __restrict__ edge_s,
      const unsigned int* __restrict__ cur32, unsigned int* __restrict__ gcn32,
      float* __restrict__ vsum, float* __restrict__ ksum,
      int N, int PG, int mB, int vsB, int ksB, int gcnB){
  int bx = blockIdx.x;
  if (bx < mB){
    int wv = threadIdx.x >> 6, l = threadIdx.x & 63;
    int b = bx >> 2;
    int gw = (bx & 3) * 4 + wv;
    int itile = gw & 7, jh = gw >> 3;
    int quad = l >> 4, lcol = l & 15;
    ffrag acc[4] = {};
    const unsigned short* Arow = ksT + (size_t)(itile * 16 + lcol) * N + (size_t)b * PG + quad * 8;
    const unsigned short* B0 = curT + (size_t)b * PG + quad * 8;
    int steps = PG / 32;
    for (int s = 0; s < steps; s++){
      bfrag a = *(const bfrag*)(Arow + s * 32);
#pragma unroll
      for (int jt = 0; jt < 4; jt++){
        bfrag bb = *(const bfrag*)(B0 + (size_t)((jh * 4 + jt) * 16 + lcol) * N + s * 32);
        acc[jt] = __builtin_amdgcn_mfma_f32_16x16x32_bf16(a, bb, acc[jt], 0, 0, 0);
      }
    }
    unsigned short* MTb = MT + (size_t)b * C * C;
    int i0 = itile * 16 + quad * 4;
#pragma unroll
    for (int jt = 0; jt < 4; jt++){
      int j = (jh * 4 + jt) * 16 + lcol;
      ushort4 pk;
      pk.x = f2bf(acc[jt][0]); pk.y = f2bf(acc[jt][1]);
      pk.z = f2bf(acc[jt][2]); pk.w = f2bf(acc[jt][3]);
      *(ushort4*)(MTb + (size_t)j * C + i0) = pk;
    }
    return;
  }
  bx -= mB;
  if (bx < vsB + ksB){
    const unsigned short* src = (bx < vsB) ? curT : ksT;
    float* dst = (bx < vsB) ? vsum : ksum;
    int b = (bx < vsB) ? bx : (bx - vsB);
    int wv = threadIdx.x >> 6, l = threadIdx.x & 63;
    for (int d = wv * 32; d < wv * 32 + 32; d++){
      float s = 0.f;
      for (int n0 = l * 8; n0 < PG; n0 += 512){
        bfrag v = *(const bfrag*)(src + (size_t)d * N + (size_t)b * PG + n0);
#pragma unroll
        for (int j = 0; j < 8; j++) s += bf2f((unsigned short)v[j]);
      }
#pragma unroll
      for (int off = 32; off; off >>= 1) s += __shfl_xor(s, off, 64);
      if (l == 0) dst[b * C + d] = s;
    }
    return;
  }
  bx -= vsB + ksB;
  if (bx < gcnB){
    int nid = bx * 4 + (threadIdx.x >> 6);
    int c = threadIdx.x & 63;                 // channel-pair index
    if (nid >= N) return;
    int s = row_ptr[nid], e = row_ptr[nid + 1];
    float a0 = 0.f, a1 = 0.f;
    int p = s;
    for (; p + 4 <= e; p += 4){
      int2 e0 = edge_s[p],     e1 = edge_s[p + 1];
      int2 e2 = edge_s[p + 2], e3 = edge_s[p + 3];
      float f0 = __int_as_float(e0.y), f1 = __int_as_float(e1.y);
      float f2 = __int_as_float(e2.y), f3 = __int_as_float(e3.y);
      unsigned int u0 = cur32[(size_t)e0.x * 64 + c];
      unsigned int u1 = cur32[(size_t)e1.x * 64 + c];
      unsigned int u2 = cur32[(size_t)e2.x * 64 + c];
      unsigned int u3 = cur32[(size_t)e3.x * 64 + c];
      a0 += f0 * bf2f((unsigned short)(u0 & 0xffffu));
      a1 += f0 * bf2f((unsigned short)(u0 >> 16));
      a0 += f1 * bf2f((unsigned short)(u1 & 0xffffu));
      a1 += f1 * bf2f((unsigned short)(u1 >> 16));
      a0 += f2 * bf2f((unsigned short)(u2 & 0xffffu));
      a1 += f2 * bf2f((unsigned short)(u2 >> 16));
      a0 += f3 * bf2f((unsigned short)(u3 & 0xffffu));
      a1 += f3 * bf2f((unsigned short)(u3 >> 16));
    }
    for (; p < e; p++){
      int2 ed = edge_s[p];
      float cf = __int_as_float(ed.y);
      unsigned int u = cur32[(size_t)ed.x * 64 + c];
      a0 += cf * bf2f((unsigned short)(u & 0xffffu));
      a1 += cf * bf2f((unsigned short)(u >> 16));
    }
    gcn32[(size_t)nid * 64 + c] = ((unsigned int)f2bf(a1) << 16) | (unsigned int)f2bf(a0);
  }
}

// ---------------- phase2 [MFMA]: cur_{it+1} = 0.5*(gcn + attn); no accumulator ----------------
__global__ __launch_bounds__(256) void k_phase2(const unsigned short* __restrict__ qs,
      const unsigned short* __restrict__ MT, const float* __restrict__ vsum,
      const float* __restrict__ denom, const unsigned short* __restrict__ gcn16,
      unsigned short* __restrict__ curO, unsigned short* __restrict__ curT,
      int N, int PG){
  int wv = threadIdx.x >> 6, l = threadIdx.x & 63;
  int m0 = (blockIdx.x * 4 + wv) * 16;
  if (m0 >= N) return;
  int b = m0 / PG;
  int quad = l >> 4, lcol = l & 15;
  ffrag acc[8] = {};
  const unsigned short* Abase = qs + (size_t)(m0 + lcol) * C + quad * 8;
  const unsigned short* MTb = MT + (size_t)b * C * C;
#pragma unroll
  for (int s = 0; s < 4; s++){
    bfrag a = *(const bfrag*)(Abase + s * 32);
#pragma unroll
    for (int dt = 0; dt < 8; dt++){
      bfrag bb = *(const bfrag*)(MTb + (size_t)(dt * 16 + lcol) * C + s * 32 + quad * 8);
      acc[dt] = __builtin_amdgcn_mfma_f32_16x16x32_bf16(a, bb, acc[dt], 0, 0, 0);
    }
  }
  float dn[4];
#pragma unroll
  for (int r = 0; r < 4; r++) dn[r] = denom[m0 + quad * 4 + r];
#pragma unroll
  for (int dt = 0; dt < 8; dt++){
    int d = dt * 16 + lcol;
    float vs = vsum[b * C + d];
    ushort4 pk;
#pragma unroll
    for (int r = 0; r < 4; r++){
      int m = m0 + quad * 4 + r;
      float attn = (acc[dt][r] + vs) / dn[r];
      float g = bf2f(gcn16[(size_t)m * C + d]);
      unsigned short nb = f2bf(0.5f * (g + attn));   // BETA = 0.5
      curO[(size_t)m * C + d] = nb;
      ((unsigned short*)&pk)[r] = nb;
    }
    *(ushort4*)(curT + (size_t)d * N + m0 + quad * 4) = pk;
  }
}

// ---------------- out = (x + c1+c2+c3+c4) @ Wo^T + Wo_b  (FP32 OUTPUT)  [MFMA] ----------------
__global__ __launch_bounds__(256) void k_final(const float* __restrict__ x,
      const unsigned short* __restrict__ c1, const unsigned short* __restrict__ c2,
      const unsigned short* __restrict__ c3, const unsigned short* __restrict__ c4,
      const unsigned short* __restrict__ Wo, const float* __restrict__ Wob,
      float* __restrict__ out, int N){
  int wv = threadIdx.x >> 6, l = threadIdx.x & 63;
  int m0 = (blockIdx.x * 4 + wv) * 16;
  if (m0 >= N) return;
  int quad = l >> 4, lcol = l & 15;
  ffrag acc[8] = {};
  size_t rowoff = (size_t)(m0 + lcol) * C + quad * 8;
#pragma unroll
  for (int s = 0; s < 4; s++){
    size_t base = rowoff + s * 32;
    float4 xa0 = *(const float4*)(x + base);
    float4 xa1 = *(const float4*)(x + base + 4);
    bfrag b1 = *(const bfrag*)(c1 + base);
    bfrag b2 = *(const bfrag*)(c2 + base);
    bfrag b3 = *(const bfrag*)(c3 + base);
    bfrag b4 = *(const bfrag*)(c4 + base);
    float xs[8] = {xa0.x, xa0.y, xa0.z, xa0.w, xa1.x, xa1.y, xa1.z, xa1.w};
    bfrag a;
#pragma unroll
    for (int j = 0; j < 8; j++){
      float v = (((xs[j] + bf2f((unsigned short)b1[j])) + bf2f((unsigned short)b2[j]))
                 + bf2f((unsigned short)b3[j])) + bf2f((unsigned short)b4[j]);
      a[j] = (short)f2bf(v);
    }
#pragma unroll
    for (int ot = 0; ot < 8; ot++){
      bfrag bb = *(const bfrag*)(Wo + (size_t)(ot * 16 + lcol) * C + s * 32 + quad * 8);
      acc[ot] = __builtin_amdgcn_mfma_f32_16x16x32_bf16(a, bb, acc[ot], 0, 0, 0);
    }
  }
#pragma unroll
  for (int ot = 0; ot < 8; ot++){
    float bias = Wob[ot * 16 + lcol];
#pragma unroll
    for (int r = 0; r < 4; r++){
      out[(size_t)(m0 + quad * 4 + r) * C + ot * 16 + lcol] = acc[ot][r] + bias;   // fp32 store
    }
  }
}

// ================= host =================

extern "C" void kernel_launch(void* const* d_in, const int* in_sizes, int n_in,
                              void* d_out, int out_size, void* d_ws, size_t ws_size,
                              hipStream_t stream){
  const float* x    = (const float*)d_in[0];
  const int*   eidx = (const int*)d_in[1];
  const float* ew   = (const float*)d_in[2];
  const int*   n_nodes = (const int*)d_in[3];
  const float* Wq_w = (const float*)d_in[4];
  const float* Wq_b = (const float*)d_in[5];
  const float* Wk_w = (const float*)d_in[6];
  const float* Wk_b = (const float*)d_in[7];
  const float* Wo_w = (const float*)d_in[8];
  const float* Wo_b = (const float*)d_in[9];
  float* out = (float*)d_out;                  // fp32 output

  int N = in_sizes[0] / C;
  int E = in_sizes[2];
  int B = in_sizes[3];
  int PG = N / B;
  int BC = B * C;
  const int* row = eidx;
  const int* col = eidx + E;

  char* p = (char*)d_ws;
  auto alloc = [&](size_t bytes) -> void* {
    void* r = (void*)p; p += (bytes + 255) & ~(size_t)255; return r;
  };
  unsigned short* cur[5];
  for (int i = 0; i < 5; i++) cur[i] = (unsigned short*)alloc((size_t)N * C * 2);
  unsigned short* curT  = (unsigned short*)alloc((size_t)N * C * 2);
  unsigned short* qs16  = (unsigned short*)alloc((size_t)N * C * 2);
  unsigned short* ksT   = (unsigned short*)alloc((size_t)N * C * 2);
  unsigned short* gcn16 = (unsigned short*)alloc((size_t)N * C * 2);
  unsigned short* MT    = (unsigned short*)alloc((size_t)B * C * C * 2);
  unsigned short* W16   = (unsigned short*)alloc((size_t)3 * C * C * 2);  // Wq|Wk|Wo
  unsigned long long* deg64 = (unsigned long long*)alloc((size_t)N * 8);
  float*          dinv  = (float*)alloc((size_t)N * 4);
  int*            row_ptr = (int*)alloc((size_t)(N + 1) * 4);
  int*            rank  = (int*)alloc((size_t)E * 4);
  int*            bsum  = (int*)alloc(1024);
  int2*           edge_s = (int2*)alloc((size_t)E * 8);
  float*          ksum  = (float*)alloc((size_t)BC * 4);
  float*          vsum  = (float*)alloc((size_t)BC * 4);
  float*          denom = (float*)alloc((size_t)N * 4);

  dim3 b256(256);
  int wblocks = (N / 16 + 3) / 4;   // one wave per 16 nodes, 4 waves/block
  int WW = C * C;
  int nscan = (N + 255) / 256;
  int degB = (E + 255) / 256;
  int castB = (3 * WW + 255) / 256;
  int fillB = (E + 255) / 256;
  int prepB = (N / 64) * (C / 64);
  int mB = 4 * B;
  int gcnB = (N + 3) / 4;
  int vsB = B;                       // vsum reduction blocks (one per graph)

  // ---- prep (6 launches) ----
  k_zero_region<<<dim3((2 * N + 255) / 256), b256, 0, stream>>>((unsigned int*)deg64, 2 * N);
  k_degcast<<<dim3(degB + castB), b256, 0, stream>>>(row, ew, deg64, rank, E,
                                                     Wq_w, Wk_w, Wo_w, W16, WW, degB);
  k_scan1<<<dim3(nscan), b256, 0, stream>>>(deg64, dinv, bsum, N);
  k_scan3<<<dim3(nscan), b256, 0, stream>>>(deg64, bsum, row_ptr, N);
  k_fillprep<<<dim3(fillB + prepB), b256, 0, stream>>>(row, col, ew, rank, row_ptr, dinv,
                                                       edge_s, E, fillB,
                                                       x, cur[0], curT, N);
  k_proj2<<<dim3(2 * wblocks), b256, 0, stream>>>(cur[0], W16, Wq_b, Wk_b,
                                                  qs16, ksT, N, wblocks);

  // ---- 4 propagation iterations ----
  for (int it = 0; it < 4; it++){
    int ksB = (it == 0) ? B : 0;     // ksum reduction rides along iteration 0
    k_mid<<<dim3(mB + vsB + ksB + gcnB), b256, 0, stream>>>(ksT, curT, MT, row_ptr, edge_s,
                                                      (const unsigned int*)cur[it],
                                                      (unsigned int*)gcn16,
                                                      vsum, ksum,
                                                      N, PG, mB, vsB, ksB, gcnB);
    if (it == 0)
      k_denom<<<dim3((N + 3) / 4), b256, 0, stream>>>(qs16, ksum, n_nodes, denom, N, PG);
    k_phase2<<<dim3(wblocks), b256, 0, stream>>>(qs16, MT, vsum, denom, gcn16,
                                                 cur[it + 1], curT, N, PG);
  }

  k_final<<<dim3(wblocks), b256, 0, stream>>>(x, cur[1], cur[2], cur[3], cur[4],
                                              W16 + 2 * WW, Wo_b, out, N);
}

// Round 5
// 381.822 us; speedup vs baseline: 1.3941x; 1.0109x over previous
//
#include <hip/hip_runtime.h>
#include <stdint.h>

#define C 128

typedef __attribute__((ext_vector_type(8))) short bfrag;   // 8 x bf16 (4 VGPRs)
typedef __attribute__((ext_vector_type(4))) float ffrag;   // 4 x f32 accum

__device__ __forceinline__ unsigned short f2bf(float f){
  union { float f; unsigned int i; } v; v.f = f;
  unsigned int x = v.i;
  unsigned int r = x + 0x7fffu + ((x >> 16) & 1u);   // round-to-nearest-even
  return (unsigned short)(r >> 16);
}
__device__ __forceinline__ float bf2f(unsigned short u){
  union { unsigned int i; float f; } v; v.i = ((unsigned int)u) << 16; return v.f;
}

// ---------------- zero deg64 ----------------
__global__ void k_zero_region(unsigned int* base, int nwords){
  int i = blockIdx.x * 256 + threadIdx.x;
  if (i < nwords) base[i] = 0u;
}

// ---------------- prep1: {deg/cnt atomics | x->cur0/curT | weight casts} ----------------
// deg64: high 32 = count, low 32 = weight in 24-bit fixed point; atomic return = rank.
__global__ __launch_bounds__(256) void k_prep1(
    const int* __restrict__ row, const float* __restrict__ w,
    unsigned long long* deg64, int* __restrict__ rank, int E, int degB,
    const float* __restrict__ x, unsigned short* __restrict__ cur0,
    unsigned short* __restrict__ curT, int N, int prepB,
    const float* __restrict__ Wq, const float* __restrict__ Wk,
    const float* __restrict__ Wo, unsigned short* __restrict__ W16, int WW){
  __shared__ unsigned short tile[64][66];
  int bx = blockIdx.x;
  if (bx < degB){
    int e = bx * 256 + threadIdx.x;
    if (e < E){
      int r = row[e];
      unsigned int wf = (unsigned int)(w[e] * 16777216.0f + 0.5f);   // w * 2^24
      unsigned long long old =
          atomicAdd(&deg64[r], 0x100000000ULL | (unsigned long long)wf);
      rank[e] = (int)(old >> 32);
    }
    return;
  }
  bx -= degB;
  if (bx < prepB){
    int ntiles = N >> 6;
    int n0 = (bx % ntiles) * 64;
    int c0 = (bx / ntiles) * 64;
    int tx = threadIdx.x & 63, ty = threadIdx.x >> 6;
    for (int r = ty; r < 64; r += 4){
      float v = x[(size_t)(n0 + r) * C + c0 + tx];
      unsigned short u = f2bf(v);
      cur0[(size_t)(n0 + r) * C + c0 + tx] = u;
      tile[r][tx] = u;
    }
    __syncthreads();
    for (int r = ty; r < 64; r += 4)
      curT[(size_t)(c0 + r) * N + n0 + tx] = tile[tx][r];
    return;
  }
  bx -= prepB;
  int i = bx * 256 + threadIdx.x;
  if (i < 3 * WW){
    const float* src = (i < WW) ? Wq : ((i < 2 * WW) ? Wk : Wo);
    int off = (i < WW) ? 0 : ((i < 2 * WW) ? WW : 2 * WW);
    W16[i] = f2bf(src[i - off]);
  }
}

// ---- scan stage 1: per-block sums of cnt (decoded from deg64) + dinv decode ----
__global__ void k_scan1(const unsigned long long* __restrict__ deg64,
                        float* __restrict__ dinv, int* bsum, int N){
  __shared__ int s[256];
  int b = blockIdx.x, t = threadIdx.x;
  int i = b * 256 + t;
  int cnt = 0;
  if (i < N){
    unsigned long long v = deg64[i];
    cnt = (int)(v >> 32);
    unsigned int lo = (unsigned int)v;
    float d = (float)lo * (1.0f / 16777216.0f);
    dinv[i] = lo > 0u ? 1.0f / sqrtf(d) : 0.f;
  }
  s[t] = cnt;
  __syncthreads();
  for (int o = 128; o; o >>= 1){ if (t < o) s[t] += s[t + o]; __syncthreads(); }
  if (t == 0) bsum[b] = s[0];
}

// ---- scan stage 2: each block sums bsum[0..b) itself, then local inclusive scan ----
__global__ void k_scan3(const unsigned long long* __restrict__ deg64,
                        const int* __restrict__ bsum, int* row_ptr, int N){
  __shared__ int s[256];
  int b = blockIdx.x, t = threadIdx.x;
  int i = b * 256 + t;
  int v = (i < N) ? (int)(deg64[i] >> 32) : 0;
  s[t] = v;
  __syncthreads();
  for (int o = 1; o < 256; o <<= 1){
    int u = (t >= o) ? s[t - o] : 0;
    __syncthreads(); s[t] += u; __syncthreads();
  }
  int base = 0;
  for (int j = 0; j < b; j++) base += bsum[j];
  int excl = base + s[t] - v;
  if (i < N) row_ptr[i] = excl;
  if (i == N - 1) row_ptr[N] = excl + v;
}

// ---------------- prep2: {CSR fill | both projections [MFMA]} ----------------
__global__ __launch_bounds__(256) void k_prep2(
    const int* __restrict__ row, const int* __restrict__ col,
    const float* __restrict__ w, const int* __restrict__ rank,
    const int* __restrict__ row_ptr, const float* __restrict__ dinv,
    int2* __restrict__ edge_s, int E, int fillB,
    const unsigned short* __restrict__ x, const unsigned short* __restrict__ W16,
    const float* __restrict__ Wq_b, const float* __restrict__ Wk_b,
    unsigned short* __restrict__ qs, unsigned short* __restrict__ ksT,
    int N, int wblocks){
  int bx = blockIdx.x;
  if (bx < fillB){
    int e = bx * 256 + threadIdx.x;
    if (e < E){
      int r = row[e], c = col[e];
      int p = row_ptr[r] + rank[e];
      float cf = dinv[r] * dinv[c] * w[e];
      int2 ed; ed.x = c; ed.y = __float_as_int(cf);
      edge_s[p] = ed;
    }
    return;
  }
  bx -= fillB;
  int transposed = bx >= wblocks;
  int lb = transposed ? bx - wblocks : bx;
  const unsigned short* W = transposed ? (W16 + C * C) : W16;
  const float* Wb = transposed ? Wk_b : Wq_b;
  unsigned short* out = transposed ? ksT : qs;

  int wv = threadIdx.x >> 6, l = threadIdx.x & 63;
  int m0 = (lb * 4 + wv) * 16;
  if (m0 >= N) return;
  int quad = l >> 4, lcol = l & 15;
  ffrag acc[8] = {};
  const unsigned short* Abase = x + (size_t)(m0 + lcol) * C + quad * 8;
#pragma unroll
  for (int s = 0; s < 4; s++){
    bfrag a = *(const bfrag*)(Abase + s * 32);
#pragma unroll
    for (int nt = 0; nt < 8; nt++){
      bfrag bb = *(const bfrag*)(W + (size_t)(nt * 16 + lcol) * C + s * 32 + quad * 8);
      acc[nt] = __builtin_amdgcn_mfma_f32_16x16x32_bf16(a, bb, acc[nt], 0, 0, 0);
    }
  }
  float q[8][4];
  float ss[4] = {0.f, 0.f, 0.f, 0.f};
#pragma unroll
  for (int nt = 0; nt < 8; nt++){
    float bias = Wb[nt * 16 + lcol];
#pragma unroll
    for (int r = 0; r < 4; r++){ float v = acc[nt][r] + bias; q[nt][r] = v; ss[r] += v * v; }
  }
#pragma unroll
  for (int off = 1; off < 16; off <<= 1){
#pragma unroll
    for (int r = 0; r < 4; r++) ss[r] += __shfl_xor(ss[r], off, 64);
  }
  float inv[4];
#pragma unroll
  for (int r = 0; r < 4; r++) inv[r] = 1.0f / sqrtf(fmaxf(ss[r], 1e-30f));
  if (!transposed){
#pragma unroll
    for (int nt = 0; nt < 8; nt++)
#pragma unroll
      for (int r = 0; r < 4; r++)
        out[(size_t)(m0 + quad * 4 + r) * C + nt * 16 + lcol] = f2bf(q[nt][r] * inv[r]);
  } else {
#pragma unroll
    for (int nt = 0; nt < 8; nt++){
      ushort4 pk;
      pk.x = f2bf(q[nt][0] * inv[0]); pk.y = f2bf(q[nt][1] * inv[1]);
      pk.z = f2bf(q[nt][2] * inv[2]); pk.w = f2bf(q[nt][3] * inv[3]);
      *(ushort4*)(out + (size_t)(nt * 16 + lcol) * N + m0 + quad * 4) = pk;
    }
  }
}

// ---------------- merged per-iteration mid kernel ----------------
// blocks [0, mB):                 M[b] = Ks_b^T Cur_b  (MFMA)
// blocks [mB, mB+vsB):            vsum[b][d] = sum_n curT[d][b*PG+n]  (direct write)
// blocks [mB+vsB, mB+vsB+ksB):    ksum[b][d] = sum_n ksT[d][b*PG+n]   (it0 only)
// rest:                           GCN CSR gather
__global__ __launch_bounds__(256) void k_mid(const unsigned short* __restrict__ ksT,
      const unsigned short* __restrict__ curT, unsigned short* __restrict__ MT,
      const int* __restrict__ row_ptr, const int2* __restrict__ edge_s,
      const unsigned int* __restrict__ cur32, unsigned int* __restrict__ gcn32,
      float* __restrict__ vsum, float* __restrict__ ksum,
      int N, int PG, int mB, int vsB, int ksB, int gcnB){
  int bx = blockIdx.x;
  if (bx < mB){
    int wv = threadIdx.x >> 6, l = threadIdx.x & 63;
    int b = bx >> 2;
    int gw = (bx & 3) * 4 + wv;
    int itile = gw & 7, jh = gw >> 3;
    int quad = l >> 4, lcol = l & 15;
    ffrag acc[4] = {};
    const unsigned short* Arow = ksT + (size_t)(itile * 16 + lcol) * N + (size_t)b * PG + quad * 8;
    const unsigned short* B0 = curT + (size_t)b * PG + quad * 8;
    int steps = PG / 32;
    for (int s = 0; s < steps; s++){
      bfrag a = *(const bfrag*)(Arow + s * 32);
#pragma unroll
      for (int jt = 0; jt < 4; jt++){
        bfrag bb = *(const bfrag*)(B0 + (size_t)((jh * 4 + jt) * 16 + lcol) * N + s * 32);
        acc[jt] = __builtin_amdgcn_mfma_f32_16x16x32_bf16(a, bb, acc[jt], 0, 0, 0);
      }
    }
    unsigned short* MTb = MT + (size_t)b * C * C;
    int i0 = itile * 16 + quad * 4;
#pragma unroll
    for (int jt = 0; jt < 4; jt++){
      int j = (jh * 4 + jt) * 16 + lcol;
      ushort4 pk;
      pk.x = f2bf(acc[jt][0]); pk.y = f2bf(acc[jt][1]);
      pk.z = f2bf(acc[jt][2]); pk.w = f2bf(acc[jt][3]);
      *(ushort4*)(MTb + (size_t)j * C + i0) = pk;
    }
    return;
  }
  bx -= mB;
  if (bx < vsB + ksB){
    const unsigned short* src = (bx < vsB) ? curT : ksT;
    float* dst = (bx < vsB) ? vsum : ksum;
    int b = (bx < vsB) ? bx : (bx - vsB);
    int wv = threadIdx.x >> 6, l = threadIdx.x & 63;
    for (int d = wv * 32; d < wv * 32 + 32; d++){
      float s = 0.f;
      for (int n0 = l * 8; n0 < PG; n0 += 512){
        bfrag v = *(const bfrag*)(src + (size_t)d * N + (size_t)b * PG + n0);
#pragma unroll
        for (int j = 0; j < 8; j++) s += bf2f((unsigned short)v[j]);
      }
#pragma unroll
      for (int off = 32; off; off >>= 1) s += __shfl_xor(s, off, 64);
      if (l == 0) dst[b * C + d] = s;
    }
    return;
  }
  bx -= vsB + ksB;
  if (bx < gcnB){
    int nid = bx * 4 + (threadIdx.x >> 6);
    int c = threadIdx.x & 63;                 // channel-pair index
    if (nid >= N) return;
    int s = row_ptr[nid], e = row_ptr[nid + 1];
    float a0 = 0.f, a1 = 0.f;
    int p = s;
    for (; p + 4 <= e; p += 4){
      int2 e0 = edge_s[p],     e1 = edge_s[p + 1];
      int2 e2 = edge_s[p + 2], e3 = edge_s[p + 3];
      float f0 = __int_as_float(e0.y), f1 = __int_as_float(e1.y);
      float f2 = __int_as_float(e2.y), f3 = __int_as_float(e3.y);
      unsigned int u0 = cur32[(size_t)e0.x * 64 + c];
      unsigned int u1 = cur32[(size_t)e1.x * 64 + c];
      unsigned int u2 = cur32[(size_t)e2.x * 64 + c];
      unsigned int u3 = cur32[(size_t)e3.x * 64 + c];
      a0 += f0 * bf2f((unsigned short)(u0 & 0xffffu));
      a1 += f0 * bf2f((unsigned short)(u0 >> 16));
      a0 += f1 * bf2f((unsigned short)(u1 & 0xffffu));
      a1 += f1 * bf2f((unsigned short)(u1 >> 16));
      a0 += f2 * bf2f((unsigned short)(u2 & 0xffffu));
      a1 += f2 * bf2f((unsigned short)(u2 >> 16));
      a0 += f3 * bf2f((unsigned short)(u3 & 0xffffu));
      a1 += f3 * bf2f((unsigned short)(u3 >> 16));
    }
    for (; p < e; p++){
      int2 ed = edge_s[p];
      float cf = __int_as_float(ed.y);
      unsigned int u = cur32[(size_t)ed.x * 64 + c];
      a0 += cf * bf2f((unsigned short)(u & 0xffffu));
      a1 += cf * bf2f((unsigned short)(u >> 16));
    }
    gcn32[(size_t)nid * 64 + c] = ((unsigned int)f2bf(a1) << 16) | (unsigned int)f2bf(a0);
  }
}

// ---------------- phase2 [MFMA]: cur_{it+1} = 0.5*(gcn + attn); it0 also computes denom ----------------
__global__ __launch_bounds__(256) void k_phase2(const unsigned short* __restrict__ qs,
      const unsigned short* __restrict__ MT, const float* __restrict__ vsum,
      const float* __restrict__ ksum, const int* __restrict__ n_nodes,
      float* __restrict__ denom, const unsigned short* __restrict__ gcn16,
      unsigned short* __restrict__ curO, unsigned short* __restrict__ curT,
      int N, int PG, int it0){
  int wv = threadIdx.x >> 6, l = threadIdx.x & 63;
  int m0 = (blockIdx.x * 4 + wv) * 16;
  if (m0 >= N) return;
  int b = m0 / PG;
  int quad = l >> 4, lcol = l & 15;
  ffrag acc[8] = {};
  const unsigned short* Abase = qs + (size_t)(m0 + lcol) * C + quad * 8;
  const unsigned short* MTb = MT + (size_t)b * C * C;
  const float* ksb = ksum + b * C;
  float dsum = 0.f;
#pragma unroll
  for (int s = 0; s < 4; s++){
    bfrag a = *(const bfrag*)(Abase + s * 32);
    if (it0){
#pragma unroll
      for (int j = 0; j < 8; j++)
        dsum += bf2f((unsigned short)a[j]) * ksb[quad * 8 + s * 32 + j];
    }
#pragma unroll
    for (int dt = 0; dt < 8; dt++){
      bfrag bb = *(const bfrag*)(MTb + (size_t)(dt * 16 + lcol) * C + s * 32 + quad * 8);
      acc[dt] = __builtin_amdgcn_mfma_f32_16x16x32_bf16(a, bb, acc[dt], 0, 0, 0);
    }
  }
  float dn[4];
  if (it0){
    // reduce over the 4 quads holding row (m0+lcol): lanes lcol, lcol+16, lcol+32, lcol+48
    dsum += __shfl_xor(dsum, 16, 64);
    dsum += __shfl_xor(dsum, 32, 64);
    float dfull = dsum + (float)n_nodes[b];
    if (quad == 0) denom[m0 + lcol] = dfull;          // persist for later iterations
#pragma unroll
    for (int r = 0; r < 4; r++) dn[r] = __shfl(dfull, quad * 4 + r, 64);
  } else {
#pragma unroll
    for (int r = 0; r < 4; r++) dn[r] = denom[m0 + quad * 4 + r];
  }
#pragma unroll
  for (int dt = 0; dt < 8; dt++){
    int d = dt * 16 + lcol;
    float vs = vsum[b * C + d];
    ushort4 pk;
#pragma unroll
    for (int r = 0; r < 4; r++){
      int m = m0 + quad * 4 + r;
      float attn = (acc[dt][r] + vs) / dn[r];
      float g = bf2f(gcn16[(size_t)m * C + d]);
      unsigned short nb = f2bf(0.5f * (g + attn));   // BETA = 0.5
      curO[(size_t)m * C + d] = nb;
      ((unsigned short*)&pk)[r] = nb;
    }
    *(ushort4*)(curT + (size_t)d * N + m0 + quad * 4) = pk;
  }
}

// ---------------- out = (x + c1+c2+c3+c4) @ Wo^T + Wo_b  (FP32 OUTPUT)  [MFMA] ----------------
__global__ __launch_bounds__(256) void k_final(const float* __restrict__ x,
      const unsigned short* __restrict__ c1, const unsigned short* __restrict__ c2,
      const unsigned short* __restrict__ c3, const unsigned short* __restrict__ c4,
      const unsigned short* __restrict__ Wo, const float* __restrict__ Wob,
      float* __restrict__ out, int N){
  int wv = threadIdx.x >> 6, l = threadIdx.x & 63;
  int m0 = (blockIdx.x * 4 + wv) * 16;
  if (m0 >= N) return;
  int quad = l >> 4, lcol = l & 15;
  ffrag acc[8] = {};
  size_t rowoff = (size_t)(m0 + lcol) * C + quad * 8;
#pragma unroll
  for (int s = 0; s < 4; s++){
    size_t base = rowoff + s * 32;
    float4 xa0 = *(const float4*)(x + base);
    float4 xa1 = *(const float4*)(x + base + 4);
    bfrag b1 = *(const bfrag*)(c1 + base);
    bfrag b2 = *(const bfrag*)(c2 + base);
    bfrag b3 = *(const bfrag*)(c3 + base);
    bfrag b4 = *(const bfrag*)(c4 + base);
    float xs[8] = {xa0.x, xa0.y, xa0.z, xa0.w, xa1.x, xa1.y, xa1.z, xa1.w};
    bfrag a;
#pragma unroll
    for (int j = 0; j < 8; j++){
      float v = (((xs[j] + bf2f((unsigned short)b1[j])) + bf2f((unsigned short)b2[j]))
                 + bf2f((unsigned short)b3[j])) + bf2f((unsigned short)b4[j]);
      a[j] = (short)f2bf(v);
    }
#pragma unroll
    for (int ot = 0; ot < 8; ot++){
      bfrag bb = *(const bfrag*)(Wo + (size_t)(ot * 16 + lcol) * C + s * 32 + quad * 8);
      acc[ot] = __builtin_amdgcn_mfma_f32_16x16x32_bf16(a, bb, acc[ot], 0, 0, 0);
    }
  }
#pragma unroll
  for (int ot = 0; ot < 8; ot++){
    float bias = Wob[ot * 16 + lcol];
#pragma unroll
    for (int r = 0; r < 4; r++){
      out[(size_t)(m0 + quad * 4 + r) * C + ot * 16 + lcol] = acc[ot][r] + bias;   // fp32 store
    }
  }
}

// ================= host =================

extern "C" void kernel_launch(void* const* d_in, const int* in_sizes, int n_in,
                              void* d_out, int out_size, void* d_ws, size_t ws_size,
                              hipStream_t stream){
  const float* x    = (const float*)d_in[0];
  const int*   eidx = (const int*)d_in[1];
  const float* ew   = (const float*)d_in[2];
  const int*   n_nodes = (const int*)d_in[3];
  const float* Wq_w = (const float*)d_in[4];
  const float* Wq_b = (const float*)d_in[5];
  const float* Wk_w = (const float*)d_in[6];
  const float* Wk_b = (const float*)d_in[7];
  const float* Wo_w = (const float*)d_in[8];
  const float* Wo_b = (const float*)d_in[9];
  float* out = (float*)d_out;                  // fp32 output

  int N = in_sizes[0] / C;
  int E = in_sizes[2];
  int B = in_sizes[3];
  int PG = N / B;
  int BC = B * C;
  const int* row = eidx;
  const int* col = eidx + E;

  char* p = (char*)d_ws;
  auto alloc = [&](size_t bytes) -> void* {
    void* r = (void*)p; p += (bytes + 255) & ~(size_t)255; return r;
  };
  unsigned short* cur[5];
  for (int i = 0; i < 5; i++) cur[i] = (unsigned short*)alloc((size_t)N * C * 2);
  unsigned short* curT  = (unsigned short*)alloc((size_t)N * C * 2);
  unsigned short* qs16  = (unsigned short*)alloc((size_t)N * C * 2);
  unsigned short* ksT   = (unsigned short*)alloc((size_t)N * C * 2);
  unsigned short* gcn16 = (unsigned short*)alloc((size_t)N * C * 2);
  unsigned short* MT    = (unsigned short*)alloc((size_t)B * C * C * 2);
  unsigned short* W16   = (unsigned short*)alloc((size_t)3 * C * C * 2);  // Wq|Wk|Wo
  unsigned long long* deg64 = (unsigned long long*)alloc((size_t)N * 8);
  float*          dinv  = (float*)alloc((size_t)N * 4);
  int*            row_ptr = (int*)alloc((size_t)(N + 1) * 4);
  int*            rank  = (int*)alloc((size_t)E * 4);
  int*            bsum  = (int*)alloc(1024);
  int2*           edge_s = (int2*)alloc((size_t)E * 8);
  float*          ksum  = (float*)alloc((size_t)BC * 4);
  float*          vsum  = (float*)alloc((size_t)BC * 4);
  float*          denom = (float*)alloc((size_t)N * 4);

  dim3 b256(256);
  int wblocks = (N / 16 + 3) / 4;   // one wave per 16 nodes, 4 waves/block
  int WW = C * C;
  int nscan = (N + 255) / 256;
  int degB = (E + 255) / 256;
  int castB = (3 * WW + 255) / 256;
  int fillB = (E + 255) / 256;
  int prepB = (N / 64) * (C / 64);
  int mB = 4 * B;
  int gcnB = (N + 3) / 4;
  int vsB = B;                       // vsum reduction blocks (one per graph)

  // ---- prep (4 launches) ----
  k_zero_region<<<dim3((2 * N + 255) / 256), b256, 0, stream>>>((unsigned int*)deg64, 2 * N);
  k_prep1<<<dim3(degB + prepB + castB), b256, 0, stream>>>(row, ew, deg64, rank, E, degB,
                                                           x, cur[0], curT, N, prepB,
                                                           Wq_w, Wk_w, Wo_w, W16, WW);
  k_scan1<<<dim3(nscan), b256, 0, stream>>>(deg64, dinv, bsum, N);
  k_scan3<<<dim3(nscan), b256, 0, stream>>>(deg64, bsum, row_ptr, N);
  k_prep2<<<dim3(fillB + 2 * wblocks), b256, 0, stream>>>(row, col, ew, rank, row_ptr, dinv,
                                                          edge_s, E, fillB,
                                                          cur[0], W16, Wq_b, Wk_b,
                                                          qs16, ksT, N, wblocks);

  // ---- 4 propagation iterations (2 launches each) ----
  for (int it = 0; it < 4; it++){
    int ksB = (it == 0) ? B : 0;     // ksum reduction rides along iteration 0
    k_mid<<<dim3(mB + vsB + ksB + gcnB), b256, 0, stream>>>(ksT, curT, MT, row_ptr, edge_s,
                                                      (const unsigned int*)cur[it],
                                                      (unsigned int*)gcn16,
                                                      vsum, ksum,
                                                      N, PG, mB, vsB, ksB, gcnB);
    k_phase2<<<dim3(wblocks), b256, 0, stream>>>(qs16, MT, vsum, ksum, n_nodes, denom,
                                                 gcn16, cur[it + 1], curT,
                                                 N, PG, (it == 0) ? 1 : 0);
  }

  k_final<<<dim3(wblocks), b256, 0, stream>>>(x, cur[1], cur[2], cur[3], cur[4],
                                              W16 + 2 * WW, Wo_b, out, N);
}